// Round 5
// baseline (422.359 us; speedup 1.0000x reference)
//
#include <hip/hip_runtime.h>
#include <math.h>

#define N_  32
#define T_  8192
#define D_  64
#define K_  64
#define CHUNKS 32
#define TOK_PER_BLOCK (T_ / CHUNKS)    // 256
#define TB 64                          // tokens per batch
#define NBATCH (TOK_PER_BLOCK / TB)    // 4
#define STATS_PER_N (K_ + 2 * K_ * D_) // 8256
#define XSTR 72                        // f16 stride for Xs/Qs/Pt rows

typedef _Float16 half_t;
typedef __attribute__((ext_vector_type(8)))  _Float16 v8h;
typedef __attribute__((ext_vector_type(4)))  float    v4f;
typedef __attribute__((ext_vector_type(16))) float    v16f;

// ---------------------------------------------------------------------------
// prep (grid 9): blocks 0..7 pack WH (f16 MFMA A-frag order, same as R4);
// block 8 computes Ap[k] = 2 log w - 0.5*sum_d(log c + mu^2/c).
// ---------------------------------------------------------------------------
__global__ void prep_kernel(const float* __restrict__ w, const float* __restrict__ mu,
                            const float* __restrict__ cv, float* __restrict__ Ap,
                            half_t* __restrict__ WH) {
    if (blockIdx.x < 8) {
#pragma unroll
        for (int i = 0; i < 4; ++i) {
            const int e = blockIdx.x * 1024 + i * 256 + threadIdx.x;  // 0..8191
            const int j = e & 7, l = (e >> 3) & 63, fs = e >> 9;
            const int tile = fs >> 2, s = fs & 3;
            const int kc = 16 * tile + (l & 15);
            const int f  = 32 * s + 8 * (l >> 4) + j;
            float val;
            if (f < 64) val = mu[kc * 64 + f] / cv[kc * 64 + f];
            else        val = -0.5f / cv[kc * 64 + (f - 64)];
            WH[e] = (half_t)val;
        }
    } else if (threadIdx.x < K_) {
        const int k = threadIdx.x;
        float acc = 0.f;
        for (int d = 0; d < D_; ++d) {
            const int idx = k * D_ + d;
            const float c = cv[idx], m = mu[idx];
            acc += logf(c) + m * m / c;
        }
        Ap[k] = 2.f * logf(w[k]) - 0.5f * acc;
    }
}

// ---------------------------------------------------------------------------
// main: grid (32, 32) = 1024 blocks, block 256 (4 waves).
// Per 64-token batch: prefetch next batch's globals into regs; stage X,X^2 to
// LDS f16 token-major; Phase A mfma 16x16x32 (resident W frags) + in-register
// softmax, p written TRANSPOSED (Pt[kc][t]); Phase B mfma 32x32x16 with b128
// A-frags from Pt, scalar gathers only for the B operand. AGPR-resident
// accumulators, one atomic flush per block.
// ---------------------------------------------------------------------------
__launch_bounds__(256, 3)
__global__ void main_kernel(const float* __restrict__ x, const float* __restrict__ Ap,
                            const half_t* __restrict__ WH, float* __restrict__ stats) {
    __shared__ half_t Xs[TB][XSTR];   // 9.0 KB
    __shared__ half_t Qs[TB][XSTR];   // 9.0 KB
    __shared__ half_t Pt[K_][XSTR];   // 9.0 KB  (transposed p: row=kc, col=token)

    const int tid  = threadIdx.x;
    const int lane = tid & 63;
    const int wv   = tid >> 6;
    const int chunk = blockIdx.x;
    const int n     = blockIdx.y;
    const int q     = lane >> 4;     // quad (Phase A)
    const int c0    = lane & 15;

    // resident weight A-frags
    v8h Wf[16];
#pragma unroll
    for (int t = 0; t < 4; ++t)
#pragma unroll
        for (int s = 0; s < 4; ++s)
            Wf[t * 4 + s] = *(const v8h*)(WH + (size_t)((t * 4 + s) * 64 + lane) * 8);

    float apv[16];
#pragma unroll
    for (int t = 0; t < 4; ++t)
#pragma unroll
        for (int r = 0; r < 4; ++r) apv[t * 4 + r] = Ap[16 * t + 4 * q + r];

    float S0loc[16];
#pragma unroll
    for (int j = 0; j < 16; ++j) S0loc[j] = 0.f;

    const int sig = wv >> 1;   // 0: s1 (B from Xs), 1: s2 (B from Qs)
    const int dh  = wv & 1;    // d-half
    v16f accB[2];
#pragma unroll
    for (int m = 0; m < 2; ++m)
#pragma unroll
        for (int r = 0; r < 16; ++r) accB[m][r] = 0.f;

    const size_t xbase = ((size_t)n * T_ + (size_t)chunk * TOK_PER_BLOCK) * (size_t)D_;
    // staging geometry: unit g = i*256+tid -> token tg = g>>3, chunk uu = g&7
    const int tg0 = tid >> 3, uu = tid & 7;          // i=0 unit
    const int tg1 = (256 + tid) >> 3;                // i=1 unit (same uu)

    // preload batch 0
    float4 R[4];
    {
        const float* xb = x + xbase;
        R[0] = *(const float4*)(xb + tg0 * 64 + uu * 8);
        R[1] = *(const float4*)(xb + tg0 * 64 + uu * 8 + 4);
        R[2] = *(const float4*)(xb + tg1 * 64 + uu * 8);
        R[3] = *(const float4*)(xb + tg1 * 64 + uu * 8 + 4);
    }

#pragma unroll 1
    for (int batch = 0; batch < NBATCH; ++batch) {
        // -------- prefetch next batch (covered by stage + A + B) --------
        float4 Rn[4];
        if (batch + 1 < NBATCH) {
            const float* xb = x + xbase + (size_t)(batch + 1) * TB * D_;
            Rn[0] = *(const float4*)(xb + tg0 * 64 + uu * 8);
            Rn[1] = *(const float4*)(xb + tg0 * 64 + uu * 8 + 4);
            Rn[2] = *(const float4*)(xb + tg1 * 64 + uu * 8);
            Rn[3] = *(const float4*)(xb + tg1 * 64 + uu * 8 + 4);
        } else {
            Rn[0] = R[0]; Rn[1] = R[1]; Rn[2] = R[2]; Rn[3] = R[3];
        }

        // -------- stage current batch from registers --------
#pragma unroll
        for (int i = 0; i < 2; ++i) {
            const int t = (i == 0) ? tg0 : tg1;
            const float4 v0 = R[2 * i], v1 = R[2 * i + 1];
            v8h xh, qh;
            xh[0] = (half_t)v0.x; xh[1] = (half_t)v0.y; xh[2] = (half_t)v0.z; xh[3] = (half_t)v0.w;
            xh[4] = (half_t)v1.x; xh[5] = (half_t)v1.y; xh[6] = (half_t)v1.z; xh[7] = (half_t)v1.w;
            qh[0] = (half_t)(v0.x * v0.x); qh[1] = (half_t)(v0.y * v0.y);
            qh[2] = (half_t)(v0.z * v0.z); qh[3] = (half_t)(v0.w * v0.w);
            qh[4] = (half_t)(v1.x * v1.x); qh[5] = (half_t)(v1.y * v1.y);
            qh[6] = (half_t)(v1.z * v1.z); qh[7] = (half_t)(v1.w * v1.w);
            *(v8h*)&Xs[t][uu * 8] = xh;
            *(v8h*)&Qs[t][uu * 8] = qh;
        }
        __syncthreads();

        // ---------------- Phase A ----------------
        {
            const int tok = 16 * wv + c0;            // this lane's token (local)
            v4f acc[4];
#pragma unroll
            for (int t = 0; t < 4; ++t) acc[t] = (v4f)(0.f);
#pragma unroll
            for (int s = 0; s < 4; ++s) {
                const half_t* src = (s < 2) ? &Xs[0][0] : &Qs[0][0];
                const int d0 = (s & 1) * 32 + q * 8;
                const v8h bf = *(const v8h*)(src + tok * XSTR + d0);
#pragma unroll
                for (int t = 0; t < 4; ++t)
                    acc[t] = __builtin_amdgcn_mfma_f32_16x16x32_f16(Wf[t * 4 + s], bf, acc[t], 0, 0, 0);
            }
            float pv[16];
            float m = -1e30f;
#pragma unroll
            for (int t = 0; t < 4; ++t)
#pragma unroll
                for (int r = 0; r < 4; ++r) {
                    const float lg = acc[t][r] + apv[t * 4 + r];
                    pv[t * 4 + r] = lg;
                    m = fmaxf(m, lg);
                }
            m = fmaxf(m, __shfl_xor(m, 16, 64));
            m = fmaxf(m, __shfl_xor(m, 32, 64));
            float ssum = 0.f;
#pragma unroll
            for (int j = 0; j < 16; ++j) { pv[j] = __expf(pv[j] - m); ssum += pv[j]; }
            ssum += __shfl_xor(ssum, 16, 64);
            ssum += __shfl_xor(ssum, 32, 64);
            const float rs = 1.f / ssum;
#pragma unroll
            for (int j = 0; j < 16; ++j) { pv[j] *= rs; S0loc[j] += pv[j]; }
            // transposed write: Pt[kc][tok], kc = 16t + 4q + r  (conflict-checked)
#pragma unroll
            for (int t = 0; t < 4; ++t)
#pragma unroll
                for (int r = 0; r < 4; ++r)
                    Pt[16 * t + 4 * q + r][tok] = (half_t)pv[t * 4 + r];
        }
        __syncthreads();

        // ---------------- Phase B ----------------
        {
            const half_t* Bsrc = (sig == 0) ? &Xs[0][0] : &Qs[0][0];
            const int m   = lane & 31;               // kc within half / d col
            const int h   = lane >> 5;
            const int d   = 32 * dh + m;
            const half_t* Arow0 = &Pt[m][0];
            const half_t* Arow1 = &Pt[32 + m][0];
#pragma unroll
            for (int st = 0; st < 4; ++st) {
                const int tB = 16 * st + 8 * h;
                const v8h a0 = *(const v8h*)(Arow0 + tB);   // b128
                const v8h a1 = *(const v8h*)(Arow1 + tB);   // b128
                v8h bf;
#pragma unroll
                for (int j = 0; j < 8; ++j)
                    bf[j] = Bsrc[(tB + j) * XSTR + d];
                accB[0] = __builtin_amdgcn_mfma_f32_32x32x16_f16(a0, bf, accB[0], 0, 0, 0);
                accB[1] = __builtin_amdgcn_mfma_f32_32x32x16_f16(a1, bf, accB[1], 0, 0, 0);
            }
        }
        __syncthreads();

        R[0] = Rn[0]; R[1] = Rn[1]; R[2] = Rn[2]; R[3] = Rn[3];
    }

    // -------- flush partials --------
    float* sb = stats + (size_t)n * STATS_PER_N;
#pragma unroll
    for (int j = 0; j < 16; ++j) {
        float v = S0loc[j];
        v += __shfl_xor(v, 1, 64);
        v += __shfl_xor(v, 2, 64);
        v += __shfl_xor(v, 4, 64);
        v += __shfl_xor(v, 8, 64);
        S0loc[j] = v;
    }
    if (c0 == 0) {
#pragma unroll
        for (int t = 0; t < 4; ++t)
#pragma unroll
            for (int r = 0; r < 4; ++r)
                atomicAdd(&sb[16 * t + 4 * q + r], S0loc[t * 4 + r]);
    }
    {
        const int d = 32 * dh + (lane & 31);
        float* dst = sb + 64 + sig * 4096;
#pragma unroll
        for (int mt = 0; mt < 2; ++mt)
#pragma unroll
            for (int r = 0; r < 16; ++r) {
                const int kc = 32 * mt + (r & 3) + 8 * (r >> 2) + 4 * (lane >> 5);
                atomicAdd(&dst[kc * 64 + d], accB[mt][r]);
            }
    }
}

// ---------------------------------------------------------------------------
// finalize (grid N): segment-based (no int div), coalesced reads/writes.
// ---------------------------------------------------------------------------
__global__ void fin_kernel(const float* __restrict__ w, const float* __restrict__ mu,
                           const float* __restrict__ cv, const float* __restrict__ stats,
                           float* __restrict__ out) {
    __shared__ float us[STATS_PER_N];   // 33 KB
    __shared__ float red[4];
    const int n   = blockIdx.x;
    const int tid = threadIdx.x;
    const float* sb = stats + (size_t)n * STATS_PER_N;

    float ss = 0.f;
    // seg A: v0 (64 elems)
    if (tid < 64) {
        const float wv = w[tid];
        const float v = (sb[tid] - (float)T_ * wv) * rsqrtf(wv);
        const float u = (v >= 0.f) ? sqrtf(v) : -sqrtf(-v);
        us[tid * 129] = u;
        ss = fmaf(u, u, ss);
    }
    // seg B: v1 (4096 elems)
#pragma unroll 1
    for (int i = 0; i < 16; ++i) {
        const int idx = i * 256 + tid;
        const int k = idx >> 6, d = idx & 63;
        const float v = (sb[64 + idx] - mu[idx] * sb[k]) * rsqrtf(w[k] * cv[idx]);
        const float u = (v >= 0.f) ? sqrtf(v) : -sqrtf(-v);
        us[k * 129 + 1 + d] = u;
        ss = fmaf(u, u, ss);
    }
    // seg C: v2 (4096 elems)
#pragma unroll 1
    for (int i = 0; i < 16; ++i) {
        const int idx = i * 256 + tid;
        const int k = idx >> 6, d = idx & 63;
        const float m_ = mu[idx], c_ = cv[idx];
        const float s1v = sb[64 + idx], s2v = sb[64 + 4096 + idx];
        const float v = (s2v - 2.f * m_ * s1v + (m_ * m_ - c_) * sb[k]) *
                        (rsqrtf(2.f * w[k]) / c_);
        const float u = (v >= 0.f) ? sqrtf(v) : -sqrtf(-v);
        us[k * 129 + 65 + d] = u;
        ss = fmaf(u, u, ss);
    }
#pragma unroll
    for (int off = 32; off > 0; off >>= 1) ss += __shfl_xor(ss, off, 64);
    if ((tid & 63) == 0) red[tid >> 6] = ss;
    __syncthreads();
    const float tot = red[0] + red[1] + red[2] + red[3];
    const float rn = rsqrtf(tot);
    for (int e = tid; e < STATS_PER_N; e += 256)
        out[(size_t)n * STATS_PER_N + e] = us[e] * rn;
}

// ---------------------------------------------------------------------------
extern "C" void kernel_launch(void* const* d_in, const int* in_sizes, int n_in,
                              void* d_out, int out_size, void* d_ws, size_t ws_size,
                              hipStream_t stream) {
    const float* x  = (const float*)d_in[0];
    const float* w  = (const float*)d_in[1];
    const float* mu = (const float*)d_in[2];
    const float* cv = (const float*)d_in[3];
    float* out = (float*)d_out;

    // ws layout: stats[N*8256] f32 | Ap[64] f32 | WH[64*128] f16
    float* stats = (float*)d_ws;
    float* Ap = stats + (size_t)N_ * STATS_PER_N;
    half_t* WH = (half_t*)(Ap + K_);

    hipMemsetAsync(stats, 0, (size_t)N_ * STATS_PER_N * sizeof(float), stream);

    prep_kernel<<<9, 256, 0, stream>>>(w, mu, cv, Ap, WH);
    main_kernel<<<dim3(CHUNKS, N_), 256, 0, stream>>>(x, Ap, WH, stats);
    fin_kernel<<<N_, 256, 0, stream>>>(w, mu, cv, stats, out);
}

// Round 6
// 164.001 us; speedup vs baseline: 2.5753x; 2.5753x over previous
//
#include <hip/hip_runtime.h>
#include <math.h>

#define N_  32
#define T_  8192
#define D_  64
#define K_  64
#define CHUNKS 32
#define TOK_PER_BLOCK (T_ / CHUNKS)    // 256
#define TB 64                          // tokens per batch
#define NBATCH (TOK_PER_BLOCK / TB)    // 4
#define STATS_PER_N (K_ + 2 * K_ * D_) // 8256
#define XSTR 72                        // f16 stride for Xs/Qs/Pt rows

typedef _Float16 half_t;
typedef __attribute__((ext_vector_type(8)))  _Float16 v8h;
typedef __attribute__((ext_vector_type(4)))  float    v4f;
typedef __attribute__((ext_vector_type(16))) float    v16f;

// ---------------------------------------------------------------------------
// prep (grid 9): blocks 0..7 pack WH (f16 MFMA A-frag order);
// block 8 computes Ap[k] = 2 log w - 0.5*sum_d(log c + mu^2/c).
// ---------------------------------------------------------------------------
__global__ void prep_kernel(const float* __restrict__ w, const float* __restrict__ mu,
                            const float* __restrict__ cv, float* __restrict__ Ap,
                            half_t* __restrict__ WH) {
    if (blockIdx.x < 8) {
#pragma unroll
        for (int i = 0; i < 4; ++i) {
            const int e = blockIdx.x * 1024 + i * 256 + threadIdx.x;  // 0..8191
            const int j = e & 7, l = (e >> 3) & 63, fs = e >> 9;
            const int tile = fs >> 2, s = fs & 3;
            const int kc = 16 * tile + (l & 15);
            const int f  = 32 * s + 8 * (l >> 4) + j;
            float val;
            if (f < 64) val = mu[kc * 64 + f] / cv[kc * 64 + f];
            else        val = -0.5f / cv[kc * 64 + (f - 64)];
            WH[e] = (half_t)val;
        }
    } else if (threadIdx.x < K_) {
        const int k = threadIdx.x;
        float acc = 0.f;
        for (int d = 0; d < D_; ++d) {
            const int idx = k * D_ + d;
            const float c = cv[idx], m = mu[idx];
            acc += logf(c) + m * m / c;
        }
        Ap[k] = 2.f * logf(w[k]) - 0.5f * acc;
    }
}

// ---------------------------------------------------------------------------
// main: grid (32, 32) = 1024 blocks, block 256 (4 waves).
// Identical compute to R5 (validated). Flush differs by mode:
//   mode 1: plain coalesced stores of this block's 8256-float partial record
//           (NO global atomics — R4/R5 were atomic-throughput-bound at ~26G/s)
//   mode 0: legacy atomicAdd into stats (fallback when ws too small)
// ---------------------------------------------------------------------------
__launch_bounds__(256, 3)
__global__ void main_kernel(const float* __restrict__ x, const float* __restrict__ Ap,
                            const half_t* __restrict__ WH, float* __restrict__ outbuf,
                            int mode) {
    __shared__ half_t Xs[TB][XSTR];   // 9.0 KB
    __shared__ half_t Qs[TB][XSTR];   // 9.0 KB
    __shared__ half_t Pt[K_][XSTR];   // 9.0 KB  (transposed p: row=kc, col=token)
    __shared__ float  s0sh[4][64];    // 1.0 KB  cross-wave s0 reduce

    const int tid  = threadIdx.x;
    const int lane = tid & 63;
    const int wv   = tid >> 6;
    const int chunk = blockIdx.x;
    const int n     = blockIdx.y;
    const int q     = lane >> 4;     // quad (Phase A)
    const int c0    = lane & 15;

    // resident weight A-frags
    v8h Wf[16];
#pragma unroll
    for (int t = 0; t < 4; ++t)
#pragma unroll
        for (int s = 0; s < 4; ++s)
            Wf[t * 4 + s] = *(const v8h*)(WH + (size_t)((t * 4 + s) * 64 + lane) * 8);

    float apv[16];
#pragma unroll
    for (int t = 0; t < 4; ++t)
#pragma unroll
        for (int r = 0; r < 4; ++r) apv[t * 4 + r] = Ap[16 * t + 4 * q + r];

    float S0loc[16];
#pragma unroll
    for (int j = 0; j < 16; ++j) S0loc[j] = 0.f;

    const int sig = wv >> 1;   // 0: s1 (B from Xs), 1: s2 (B from Qs)
    const int dh  = wv & 1;    // d-half
    v16f accB[2];
#pragma unroll
    for (int m = 0; m < 2; ++m)
#pragma unroll
        for (int r = 0; r < 16; ++r) accB[m][r] = 0.f;

    const size_t xbase = ((size_t)n * T_ + (size_t)chunk * TOK_PER_BLOCK) * (size_t)D_;
    const int tg0 = tid >> 3, uu = tid & 7;
    const int tg1 = (256 + tid) >> 3;

    // preload batch 0
    float4 R[4];
    {
        const float* xb = x + xbase;
        R[0] = *(const float4*)(xb + tg0 * 64 + uu * 8);
        R[1] = *(const float4*)(xb + tg0 * 64 + uu * 8 + 4);
        R[2] = *(const float4*)(xb + tg1 * 64 + uu * 8);
        R[3] = *(const float4*)(xb + tg1 * 64 + uu * 8 + 4);
    }

#pragma unroll 1
    for (int batch = 0; batch < NBATCH; ++batch) {
        // -------- prefetch next batch --------
        float4 Rn[4];
        if (batch + 1 < NBATCH) {
            const float* xb = x + xbase + (size_t)(batch + 1) * TB * D_;
            Rn[0] = *(const float4*)(xb + tg0 * 64 + uu * 8);
            Rn[1] = *(const float4*)(xb + tg0 * 64 + uu * 8 + 4);
            Rn[2] = *(const float4*)(xb + tg1 * 64 + uu * 8);
            Rn[3] = *(const float4*)(xb + tg1 * 64 + uu * 8 + 4);
        } else {
            Rn[0] = R[0]; Rn[1] = R[1]; Rn[2] = R[2]; Rn[3] = R[3];
        }

        // -------- stage current batch from registers --------
#pragma unroll
        for (int i = 0; i < 2; ++i) {
            const int t = (i == 0) ? tg0 : tg1;
            const float4 v0 = R[2 * i], v1 = R[2 * i + 1];
            v8h xh, qh;
            xh[0] = (half_t)v0.x; xh[1] = (half_t)v0.y; xh[2] = (half_t)v0.z; xh[3] = (half_t)v0.w;
            xh[4] = (half_t)v1.x; xh[5] = (half_t)v1.y; xh[6] = (half_t)v1.z; xh[7] = (half_t)v1.w;
            qh[0] = (half_t)(v0.x * v0.x); qh[1] = (half_t)(v0.y * v0.y);
            qh[2] = (half_t)(v0.z * v0.z); qh[3] = (half_t)(v0.w * v0.w);
            qh[4] = (half_t)(v1.x * v1.x); qh[5] = (half_t)(v1.y * v1.y);
            qh[6] = (half_t)(v1.z * v1.z); qh[7] = (half_t)(v1.w * v1.w);
            *(v8h*)&Xs[t][uu * 8] = xh;
            *(v8h*)&Qs[t][uu * 8] = qh;
        }
        __syncthreads();

        // ---------------- Phase A ----------------
        {
            const int tok = 16 * wv + c0;
            v4f acc[4];
#pragma unroll
            for (int t = 0; t < 4; ++t) acc[t] = (v4f)(0.f);
#pragma unroll
            for (int s = 0; s < 4; ++s) {
                const half_t* src = (s < 2) ? &Xs[0][0] : &Qs[0][0];
                const int d0 = (s & 1) * 32 + q * 8;
                const v8h bf = *(const v8h*)(src + tok * XSTR + d0);
#pragma unroll
                for (int t = 0; t < 4; ++t)
                    acc[t] = __builtin_amdgcn_mfma_f32_16x16x32_f16(Wf[t * 4 + s], bf, acc[t], 0, 0, 0);
            }
            float pv[16];
            float m = -1e30f;
#pragma unroll
            for (int t = 0; t < 4; ++t)
#pragma unroll
                for (int r = 0; r < 4; ++r) {
                    const float lg = acc[t][r] + apv[t * 4 + r];
                    pv[t * 4 + r] = lg;
                    m = fmaxf(m, lg);
                }
            m = fmaxf(m, __shfl_xor(m, 16, 64));
            m = fmaxf(m, __shfl_xor(m, 32, 64));
            float ssum = 0.f;
#pragma unroll
            for (int j = 0; j < 16; ++j) { pv[j] = __expf(pv[j] - m); ssum += pv[j]; }
            ssum += __shfl_xor(ssum, 16, 64);
            ssum += __shfl_xor(ssum, 32, 64);
            const float rs = 1.f / ssum;
#pragma unroll
            for (int j = 0; j < 16; ++j) { pv[j] *= rs; S0loc[j] += pv[j]; }
#pragma unroll
            for (int t = 0; t < 4; ++t)
#pragma unroll
                for (int r = 0; r < 4; ++r)
                    Pt[16 * t + 4 * q + r][tok] = (half_t)pv[t * 4 + r];
        }
        __syncthreads();

        // ---------------- Phase B ----------------
        {
            const half_t* Bsrc = (sig == 0) ? &Xs[0][0] : &Qs[0][0];
            const int m   = lane & 31;
            const int h   = lane >> 5;
            const int d   = 32 * dh + m;
            const half_t* Arow0 = &Pt[m][0];
            const half_t* Arow1 = &Pt[32 + m][0];
#pragma unroll
            for (int st = 0; st < 4; ++st) {
                const int tB = 16 * st + 8 * h;
                const v8h a0 = *(const v8h*)(Arow0 + tB);
                const v8h a1 = *(const v8h*)(Arow1 + tB);
                v8h bf;
#pragma unroll
                for (int j = 0; j < 8; ++j)
                    bf[j] = Bsrc[(tB + j) * XSTR + d];
                accB[0] = __builtin_amdgcn_mfma_f32_32x32x16_f16(a0, bf, accB[0], 0, 0, 0);
                accB[1] = __builtin_amdgcn_mfma_f32_32x32x16_f16(a1, bf, accB[1], 0, 0, 0);
            }
        }
        __syncthreads();

        R[0] = Rn[0]; R[1] = Rn[1]; R[2] = Rn[2]; R[3] = Rn[3];
    }

    // -------- flush: block-level s0 via LDS, then stores (mode1) / atomics (mode0) --------
#pragma unroll
    for (int j = 0; j < 16; ++j) {
        float v = S0loc[j];
        v += __shfl_xor(v, 1, 64);
        v += __shfl_xor(v, 2, 64);
        v += __shfl_xor(v, 4, 64);
        v += __shfl_xor(v, 8, 64);
        S0loc[j] = v;
    }
    if (c0 == 0) {
#pragma unroll
        for (int t = 0; t < 4; ++t)
#pragma unroll
            for (int r = 0; r < 4; ++r)
                s0sh[wv][16 * t + 4 * q + r] = S0loc[t * 4 + r];
    }
    __syncthreads();

    if (mode == 1) {
        float* dstb = outbuf + (size_t)(n * CHUNKS + chunk) * STATS_PER_N;
        if (tid < 64)
            dstb[tid] = s0sh[0][tid] + s0sh[1][tid] + s0sh[2][tid] + s0sh[3][tid];
        const int d = 32 * dh + (lane & 31);
        float* dst = dstb + 64 + sig * 4096;
#pragma unroll
        for (int mt = 0; mt < 2; ++mt)
#pragma unroll
            for (int r = 0; r < 16; ++r) {
                const int kc = 32 * mt + (r & 3) + 8 * (r >> 2) + 4 * (lane >> 5);
                dst[kc * 64 + d] = accB[mt][r];
            }
    } else {
        float* sb = outbuf + (size_t)n * STATS_PER_N;
        if (tid < 64)
            atomicAdd(&sb[tid], s0sh[0][tid] + s0sh[1][tid] + s0sh[2][tid] + s0sh[3][tid]);
        const int d = 32 * dh + (lane & 31);
        float* dst = sb + 64 + sig * 4096;
#pragma unroll
        for (int mt = 0; mt < 2; ++mt)
#pragma unroll
            for (int r = 0; r < 16; ++r) {
                const int kc = 32 * mt + (r & 3) + 8 * (r >> 2) + 4 * (lane >> 5);
                atomicAdd(&dst[kc * 64 + d], accB[mt][r]);
            }
    }
}

// ---------------------------------------------------------------------------
// reduce (mode1): stats[n][e] = sum_c partials[n][c][e]. grid (33, N_).
// ---------------------------------------------------------------------------
__global__ void reduce_kernel(const float* __restrict__ partials, float* __restrict__ stats) {
    const int e = blockIdx.x * 256 + threadIdx.x;
    const int n = blockIdx.y;
    if (e >= STATS_PER_N) return;
    const float* src = partials + (size_t)n * CHUNKS * STATS_PER_N + e;
    float acc = 0.f;
#pragma unroll 8
    for (int c = 0; c < CHUNKS; ++c)
        acc += src[(size_t)c * STATS_PER_N];
    stats[(size_t)n * STATS_PER_N + e] = acc;
}

// ---------------------------------------------------------------------------
// finalize (grid N): segment-based, coalesced.
// ---------------------------------------------------------------------------
__global__ void fin_kernel(const float* __restrict__ w, const float* __restrict__ mu,
                           const float* __restrict__ cv, const float* __restrict__ stats,
                           float* __restrict__ out) {
    __shared__ float us[STATS_PER_N];   // 33 KB
    __shared__ float red[4];
    const int n   = blockIdx.x;
    const int tid = threadIdx.x;
    const float* sb = stats + (size_t)n * STATS_PER_N;

    float ss = 0.f;
    if (tid < 64) {
        const float wv = w[tid];
        const float v = (sb[tid] - (float)T_ * wv) * rsqrtf(wv);
        const float u = (v >= 0.f) ? sqrtf(v) : -sqrtf(-v);
        us[tid * 129] = u;
        ss = fmaf(u, u, ss);
    }
#pragma unroll 1
    for (int i = 0; i < 16; ++i) {
        const int idx = i * 256 + tid;
        const int k = idx >> 6, d = idx & 63;
        const float v = (sb[64 + idx] - mu[idx] * sb[k]) * rsqrtf(w[k] * cv[idx]);
        const float u = (v >= 0.f) ? sqrtf(v) : -sqrtf(-v);
        us[k * 129 + 1 + d] = u;
        ss = fmaf(u, u, ss);
    }
#pragma unroll 1
    for (int i = 0; i < 16; ++i) {
        const int idx = i * 256 + tid;
        const int k = idx >> 6, d = idx & 63;
        const float m_ = mu[idx], c_ = cv[idx];
        const float s1v = sb[64 + idx], s2v = sb[64 + 4096 + idx];
        const float v = (s2v - 2.f * m_ * s1v + (m_ * m_ - c_) * sb[k]) *
                        (rsqrtf(2.f * w[k]) / c_);
        const float u = (v >= 0.f) ? sqrtf(v) : -sqrtf(-v);
        us[k * 129 + 65 + d] = u;
        ss = fmaf(u, u, ss);
    }
#pragma unroll
    for (int off = 32; off > 0; off >>= 1) ss += __shfl_xor(ss, off, 64);
    if ((tid & 63) == 0) red[tid >> 6] = ss;
    __syncthreads();
    const float tot = red[0] + red[1] + red[2] + red[3];
    const float rn = rsqrtf(tot);
    for (int e = tid; e < STATS_PER_N; e += 256)
        out[(size_t)n * STATS_PER_N + e] = us[e] * rn;
}

// ---------------------------------------------------------------------------
extern "C" void kernel_launch(void* const* d_in, const int* in_sizes, int n_in,
                              void* d_out, int out_size, void* d_ws, size_t ws_size,
                              hipStream_t stream) {
    const float* x  = (const float*)d_in[0];
    const float* w  = (const float*)d_in[1];
    const float* mu = (const float*)d_in[2];
    const float* cv = (const float*)d_in[3];
    float* out = (float*)d_out;

    const size_t part_elems  = (size_t)CHUNKS * N_ * STATS_PER_N;   // 8.45M floats
    const size_t stats_elems = (size_t)N_ * STATS_PER_N;
    const size_t wh_felems   = (size_t)K_ * 64;                      // 8192 f16 = 4096 f32
    const size_t need_big = (part_elems + stats_elems + K_ + wh_felems) * sizeof(float);

    if (ws_size >= need_big) {
        // partials path — no global atomics
        float* partials = (float*)d_ws;
        float* stats = partials + part_elems;
        float* Ap = stats + stats_elems;
        half_t* WH = (half_t*)(Ap + K_);

        prep_kernel<<<9, 256, 0, stream>>>(w, mu, cv, Ap, WH);
        main_kernel<<<dim3(CHUNKS, N_), 256, 0, stream>>>(x, Ap, WH, partials, 1);
        reduce_kernel<<<dim3(33, N_), 256, 0, stream>>>(partials, stats);
        fin_kernel<<<N_, 256, 0, stream>>>(w, mu, cv, stats, out);
    } else {
        // fallback: atomic path (R5 behavior)
        float* stats = (float*)d_ws;
        float* Ap = stats + stats_elems;
        half_t* WH = (half_t*)(Ap + K_);

        hipMemsetAsync(stats, 0, stats_elems * sizeof(float), stream);
        prep_kernel<<<9, 256, 0, stream>>>(w, mu, cv, Ap, WH);
        main_kernel<<<dim3(CHUNKS, N_), 256, 0, stream>>>(x, Ap, WH, stats, 0);
        fin_kernel<<<N_, 256, 0, stream>>>(w, mu, cv, stats, out);
    }
}